// Round 1
// baseline (433.952 us; speedup 1.0000x reference)
//
#include <hip/hip_runtime.h>
#include <stdint.h>

// Qwen2 attention layer: B=1, S=2048, H=4096, NH=32, NKV=4, HD=128, causal GQA + RoPE.
// Pipeline: cvt(fp32->bf16) -> QKV gemm_bt (bf16 MFMA) -> RoPE(+q scale) -> V transpose
//           -> flash attention (online softmax) -> O gemm_bt (fp32 out).

using bf16x8 = __attribute__((ext_vector_type(8))) short;          // MFMA A/B frag (8 bf16, 4 VGPR)
using f32x4  = __attribute__((ext_vector_type(4))) float;          // MFMA C/D frag
using u16    = unsigned short;
using u16x8  = __attribute__((ext_vector_type(8))) unsigned short; // 16B copy type

#define S_TOK   2048
#define HID     4096
#define QKV_N   5120   // 4096 q + 512 k + 512 v
#define K_OFF   4096
#define V_OFF   4608
#define NHEAD   32
#define NKVH    4

__device__ __forceinline__ float bf2f(u16 u) {
  unsigned v = ((unsigned)u) << 16;
  return __builtin_bit_cast(float, v);
}
__device__ __forceinline__ u16 f2bf(float f) {   // round-to-nearest-even
  unsigned u = __builtin_bit_cast(unsigned, f);
  u += 0x7fffu + ((u >> 16) & 1u);
  return (u16)(u >> 16);
}

// ---------------- fp32 -> bf16 convert (vectorized, grid-stride) ----------------
__global__ void cvt_kernel(const float* __restrict__ src, u16* __restrict__ dst, int n4) {
  int stride = gridDim.x * blockDim.x;
  for (int i = blockIdx.x * blockDim.x + threadIdx.x; i < n4; i += stride) {
    f32x4 v = ((const f32x4*)src)[i];
    union { u16 a[4]; unsigned long long ll; } o;
    o.a[0] = f2bf(v[0]); o.a[1] = f2bf(v[1]); o.a[2] = f2bf(v[2]); o.a[3] = f2bf(v[3]);
    ((unsigned long long*)dst)[i] = o.ll;
  }
}

// ---------------- bias concat (q_b | k_b | v_b) -> fp32[5120] ----------------
__global__ void biascat_kernel(const float* __restrict__ qb, const float* __restrict__ kb,
                               const float* __restrict__ vb, float* __restrict__ out) {
  int i = blockIdx.x * 256 + threadIdx.x;
  if (i >= QKV_N) return;
  float v;
  if (i < K_OFF) v = qb[i];
  else if (i < V_OFF) v = kb[i - K_OFF];
  else v = vb[i - V_OFF];
  out[i] = v;
}

// ---------------- async global->LDS (16B per lane, dest = base + lane*16) ----------------
__device__ __forceinline__ void gload_lds16(const void* g, void* l) {
  __builtin_amdgcn_global_load_lds(
      (const __attribute__((address_space(1))) void*)g,
      (__attribute__((address_space(3))) void*)l, 16, 0, 0);
}

// ---------------- GEMM: C[M,N] = A[M,K] @ B[N,K]^T (+bias), bf16 in, fp32 acc ----------------
// m97 structure: 128x128 tile, BK=64, 4 waves (2x2 of 64x64), 16x16x32 bf16 MFMA,
// global_load_lds width 16, single-buffered LDS, 2 barriers per K-step.
template <int BF16OUT, int BIAS>
__global__ __launch_bounds__(256, 2)
void gemm_bt_kernel(const u16* __restrict__ A, const u16* __restrict__ Bm,
                    void* __restrict__ C, const float* __restrict__ bias,
                    int M, int N, int K) {
  __shared__ __align__(16) u16 lA[128 * 64];
  __shared__ __align__(16) u16 lB[128 * 64];
  const int tid  = threadIdx.x;
  const int wave = tid >> 6, lane = tid & 63;
  const int lg = lane >> 4, l15 = lane & 15;
  const int m0 = blockIdx.y * 128, n0 = blockIdx.x * 128;
  const int wr = wave >> 1, wc = wave & 1;

  f32x4 acc[4][4] = {};

  for (int k0 = 0; k0 < K; k0 += 64) {
#pragma unroll
    for (int i = 0; i < 4; ++i) {
      int c = wave * 4 + i;          // chunk 0..15, 1KB each (64 lanes x 16B)
      int s = c * 64 + lane;         // slot -> row/col of [128][64] tile
      int row = s >> 3;
      int col = (s & 7) << 3;
      gload_lds16(A  + (size_t)(m0 + row) * K + k0 + col, &lA[c * 512]);
      gload_lds16(Bm + (size_t)(n0 + row) * K + k0 + col, &lB[c * 512]);
    }
    __syncthreads();                 // drains vmcnt before barrier (compiler-emitted)
#pragma unroll
    for (int kk = 0; kk < 2; ++kk) {
      bf16x8 af[4], bfr[4];
#pragma unroll
      for (int mi = 0; mi < 4; ++mi)
        af[mi] = *(const bf16x8*)&lA[(wr * 64 + mi * 16 + l15) * 64 + kk * 32 + lg * 8];
#pragma unroll
      for (int ni = 0; ni < 4; ++ni)
        bfr[ni] = *(const bf16x8*)&lB[(wc * 64 + ni * 16 + l15) * 64 + kk * 32 + lg * 8];
#pragma unroll
      for (int mi = 0; mi < 4; ++mi)
#pragma unroll
        for (int ni = 0; ni < 4; ++ni)
          acc[mi][ni] = __builtin_amdgcn_mfma_f32_16x16x32_bf16(af[mi], bfr[ni], acc[mi][ni], 0, 0, 0);
    }
    __syncthreads();
  }

  // epilogue: D layout col=lane&15, row=(lane>>4)*4+reg  [m89-verified]
#pragma unroll
  for (int mi = 0; mi < 4; ++mi) {
#pragma unroll
    for (int ni = 0; ni < 4; ++ni) {
      int r0 = m0 + wr * 64 + mi * 16 + lg * 4;
      int cc = n0 + wc * 64 + ni * 16 + l15;
      float bv = BIAS ? bias[cc] : 0.0f;
#pragma unroll
      for (int r = 0; r < 4; ++r) {
        float v = acc[mi][ni][r] + bv;
        if (BF16OUT) ((u16*)C)[(size_t)(r0 + r) * N + cc] = f2bf(v);
        else         ((float*)C)[(size_t)(r0 + r) * N + cc] = v;
      }
    }
  }
}

// ---------------- RoPE in-place on q,k regions of qkv; folds 1/sqrt(HD) into q ----------------
__global__ void rope_kernel(u16* __restrict__ qkv, const int* __restrict__ pos_ids) {
  const int tid  = threadIdx.x;
  const int gid  = blockIdx.x * 4 + (tid >> 6);   // (s, head) pair; 2048*36 total
  const int lane = tid & 63;                       // d in [0,64)
  const int s = gid / 36, hh = gid - s * 36;       // hh: 0..31 q heads, 32..35 k heads
  const float pos = (float)pos_ids[s];
  const float inv = exp2f((float)lane * -0.20762050593f);  // 10000^(-d/64)
  float sn, cs;
  sincosf(pos * inv, &sn, &cs);
  size_t base = (size_t)s * QKV_N + (hh < 32 ? hh * 128 : K_OFF + (hh - 32) * 128);
  float x1 = bf2f(qkv[base + lane]);
  float x2 = bf2f(qkv[base + lane + 64]);
  float o1 = x1 * cs - x2 * sn;
  float o2 = x2 * cs + x1 * sn;
  if (hh < 32) { o1 *= 0.08838834764831845f; o2 *= 0.08838834764831845f; }
  qkv[base + lane]      = f2bf(o1);
  qkv[base + lane + 64] = f2bf(o2);
}

// ---------------- V transpose: qkv v-cols [2048][512] -> vt [512][2048] ----------------
__global__ void vtrans_kernel(const u16* __restrict__ qkv, u16* __restrict__ vt) {
  __shared__ u16 t[32][33];
  const int tx = threadIdx.x & 31, ty = threadIdx.x >> 5;  // 32x8
  const int bc = blockIdx.x;  // 16 col tiles (512/32)
  const int bs = blockIdx.y;  // 64 row tiles (2048/32)
#pragma unroll
  for (int i = 0; i < 4; ++i)
    t[ty + i * 8][tx] = qkv[(size_t)(bs * 32 + ty + i * 8) * QKV_N + V_OFF + bc * 32 + tx];
  __syncthreads();
#pragma unroll
  for (int i = 0; i < 4; ++i)
    vt[(size_t)(bc * 32 + ty + i * 8) * S_TOK + bs * 32 + tx] = t[tx][ty + i * 8];
}

// ---------------- Flash attention: 1 WG = one head x 64 q-rows, 4 waves x 16 rows ----------------
__global__ __launch_bounds__(256, 2)
void attn_kernel(const u16* __restrict__ qkv, const u16* __restrict__ vt,
                 u16* __restrict__ aout) {
  __shared__ __align__(16) u16 Kl[64 * 128];      // K tile, XOR-swizzled rows (256B)
  __shared__ __align__(16) u16 Vl[128 * 64];      // V^T tile, XOR-swizzled rows (128B)
  __shared__ __align__(16) u16 Pl[4 * 16 * 64];   // per-wave P, XOR-swizzled rows (128B)
  const int tid = threadIdx.x, wave = tid >> 6, lane = tid & 63;
  const int lg = lane >> 4, l15 = lane & 15;
  const int qt = 31 - blockIdx.x;                 // longest blocks first
  const int h = blockIdx.y, kvh = h >> 3;
  const int q0 = qt * 64;

  // Q fragments hoisted to registers (A-frag: row = lane&15, k = (lane>>4)*8, +kk*32)
  bf16x8 qf[4];
  {
    const u16* qp = qkv + (size_t)(q0 + wave * 16 + l15) * QKV_N + h * 128 + lg * 8;
#pragma unroll
    for (int kk = 0; kk < 4; ++kk) qf[kk] = *(const bf16x8*)(qp + kk * 32);
  }
  f32x4 o[8];
#pragma unroll
  for (int i = 0; i < 8; ++i) o[i] = f32x4{0.f, 0.f, 0.f, 0.f};
  float mrow[4] = {-3e38f, -3e38f, -3e38f, -3e38f};
  float lrow[4] = {0.f, 0.f, 0.f, 0.f};

  for (int t = 0; t <= qt; ++t) {
    const int kv0 = t * 64;
    // stage K tile [64 kv][128 d], swizzle byte ^= (row&7)<<4
#pragma unroll
    for (int i = 0; i < 4; ++i) {
      int c = tid + i * 256;                 // 1024 chunks of 16B
      int row = c >> 4, ch = c & 15;
      u16x8 val = *(const u16x8*)(qkv + (size_t)(kv0 + row) * QKV_N + K_OFF + kvh * 128 + ch * 8);
      *(u16x8*)((char*)Kl + row * 256 + ((ch * 16) ^ ((row & 7) << 4))) = val;
    }
    // stage V^T tile [128 d][64 kv], swizzle byte ^= (d&7)<<4
#pragma unroll
    for (int i = 0; i < 4; ++i) {
      int c = tid + i * 256;
      int d = c >> 3, ch = c & 7;
      u16x8 val = *(const u16x8*)(vt + (size_t)(kvh * 128 + d) * S_TOK + kv0 + ch * 8);
      *(u16x8*)((char*)Vl + d * 128 + ((ch * 16) ^ ((d & 7) << 4))) = val;
    }
    __syncthreads();

    // S = Q K^T (per wave: 16 rows x 64 cols = 4 j-frags, K over d=128)
    f32x4 sc[4];
#pragma unroll
    for (int jb = 0; jb < 4; ++jb) {
      f32x4 a = {0.f, 0.f, 0.f, 0.f};
      int j = jb * 16 + l15;
      const char* kb = (const char*)Kl + j * 256;
      int swz = (j & 7) << 4;
#pragma unroll
      for (int kk = 0; kk < 4; ++kk) {
        bf16x8 bfr = *(const bf16x8*)(kb + (((kk * 32 + lg * 8) * 2) ^ swz));
        a = __builtin_amdgcn_mfma_f32_16x16x32_bf16(qf[kk], bfr, a, 0, 0, 0);
      }
      sc[jb] = a;
    }

    // causal mask (diagonal tile) + online softmax; rows r_local = lg*4+r
    const bool diag = (t == qt);
    float tmax[4] = {-3e38f, -3e38f, -3e38f, -3e38f};
#pragma unroll
    for (int jb = 0; jb < 4; ++jb) {
      int jg = kv0 + jb * 16 + l15;
#pragma unroll
      for (int r = 0; r < 4; ++r) {
        float v = sc[jb][r];
        if (diag && (jg > q0 + wave * 16 + lg * 4 + r)) v = -3e38f;
        sc[jb][r] = v;
        tmax[r] = fmaxf(tmax[r], v);
      }
    }
#pragma unroll
    for (int off = 1; off < 16; off <<= 1)
#pragma unroll
      for (int r = 0; r < 4; ++r) tmax[r] = fmaxf(tmax[r], __shfl_xor(tmax[r], off, 64));
    float alpha[4], psum[4];
#pragma unroll
    for (int r = 0; r < 4; ++r) {
      float mn = fmaxf(mrow[r], tmax[r]);
      alpha[r] = __expf(mrow[r] - mn);   // first tile: exp(-3e38-finite) -> 0
      mrow[r] = mn;
      psum[r] = 0.f;
    }
#pragma unroll
    for (int jb = 0; jb < 4; ++jb)
#pragma unroll
      for (int r = 0; r < 4; ++r) {
        float p = __expf(sc[jb][r] - mrow[r]);
        sc[jb][r] = p;
        psum[r] += p;
      }
#pragma unroll
    for (int off = 1; off < 16; off <<= 1)
#pragma unroll
      for (int r = 0; r < 4; ++r) psum[r] += __shfl_xor(psum[r], off, 64);
#pragma unroll
    for (int r = 0; r < 4; ++r) lrow[r] = lrow[r] * alpha[r] + psum[r];
#pragma unroll
    for (int db = 0; db < 8; ++db)
#pragma unroll
      for (int r = 0; r < 4; ++r) o[db][r] *= alpha[r];

    // write P (bf16) to per-wave LDS region, swizzled rows of 128B
    {
      char* pw = (char*)(Pl + wave * 1024);
#pragma unroll
      for (int jb = 0; jb < 4; ++jb)
#pragma unroll
        for (int r = 0; r < 4; ++r) {
          int prow = lg * 4 + r;
          int pcol = jb * 16 + l15;
          *(u16*)(pw + prow * 128 + ((pcol * 2) ^ ((prow & 7) << 4))) = f2bf(sc[jb][r]);
        }
    }
    __syncthreads();

    // O += P V  (A-frag from Pl, B-frag from Vl; K = 64 -> 2 MFMAs per d-frag)
    {
      const char* pr = (const char*)(Pl + wave * 1024);
      int pswz = (l15 & 7) << 4;
      bf16x8 pa0 = *(const bf16x8*)(pr + l15 * 128 + (((lg * 8) * 2) ^ pswz));
      bf16x8 pa1 = *(const bf16x8*)(pr + l15 * 128 + (((32 + lg * 8) * 2) ^ pswz));
#pragma unroll
      for (int db = 0; db < 8; ++db) {
        int d = db * 16 + l15;
        const char* vb = (const char*)Vl + d * 128;
        int vswz = (d & 7) << 4;
        bf16x8 b0 = *(const bf16x8*)(vb + (((lg * 8) * 2) ^ vswz));
        bf16x8 b1 = *(const bf16x8*)(vb + (((32 + lg * 8) * 2) ^ vswz));
        o[db] = __builtin_amdgcn_mfma_f32_16x16x32_bf16(pa0, b0, o[db], 0, 0, 0);
        o[db] = __builtin_amdgcn_mfma_f32_16x16x32_bf16(pa1, b1, o[db], 0, 0, 0);
      }
    }
    __syncthreads();
  }

  // epilogue: aout[s][h*128+d] = o / l
#pragma unroll
  for (int db = 0; db < 8; ++db) {
    int col = h * 128 + db * 16 + l15;
#pragma unroll
    for (int r = 0; r < 4; ++r) {
      int row = q0 + wave * 16 + lg * 4 + r;
      aout[(size_t)row * HID + col] = f2bf(o[db][r] / lrow[r]);
    }
  }
}

// ---------------- host launch ----------------
extern "C" void kernel_launch(void* const* d_in, const int* in_sizes, int n_in,
                              void* d_out, int out_size, void* d_ws, size_t ws_size,
                              hipStream_t stream) {
  (void)in_sizes; (void)n_in; (void)out_size; (void)ws_size;
  const float* hs  = (const float*)d_in[0];
  const float* q_w = (const float*)d_in[1];
  const float* q_b = (const float*)d_in[2];
  const float* k_w = (const float*)d_in[3];
  const float* k_b = (const float*)d_in[4];
  const float* v_w = (const float*)d_in[5];
  const float* v_b = (const float*)d_in[6];
  const float* o_w = (const float*)d_in[7];
  const int*   pos = (const int*)d_in[8];

  char* ws = (char*)d_ws;
  u16*   xbf   = (u16*)(ws);                          // [2048][4096]   16.78 MB
  u16*   wqkv  = (u16*)(ws + 16777216);               // [5120][4096]   41.94 MB
  u16*   owbf  = (u16*)(ws + 58720256);               // [4096][4096]   33.55 MB
  float* bias  = (float*)(ws + 92274688);             // [5120]          0.02 MB
  u16*   qkv   = (u16*)(ws + 92295168);               // [2048][5120]   20.97 MB
  u16*   vt    = (u16*)(ws + 113266688);              // [512][2048]     2.10 MB
  u16*   aout  = (u16*)(ws + 115363840);              // [2048][4096]   16.78 MB
  // total 132,141,056 B

  cvt_kernel<<<1024, 256, 0, stream>>>(hs,  xbf,                   (2048 * 4096) / 4);
  cvt_kernel<<<1024, 256, 0, stream>>>(q_w, wqkv,                  (4096 * 4096) / 4);
  cvt_kernel<<<512,  256, 0, stream>>>(k_w, wqkv + 4096 * 4096,    (512 * 4096) / 4);
  cvt_kernel<<<512,  256, 0, stream>>>(v_w, wqkv + 4608 * 4096,    (512 * 4096) / 4);
  cvt_kernel<<<1024, 256, 0, stream>>>(o_w, owbf,                  (4096 * 4096) / 4);
  biascat_kernel<<<20, 256, 0, stream>>>(q_b, k_b, v_b, bias);

  gemm_bt_kernel<1, 1><<<dim3(QKV_N / 128, S_TOK / 128), 256, 0, stream>>>(
      xbf, wqkv, qkv, bias, S_TOK, QKV_N, HID);

  rope_kernel<<<(S_TOK * 36) / 4, 256, 0, stream>>>(qkv, pos);
  vtrans_kernel<<<dim3(16, 64), 256, 0, stream>>>(qkv, vt);

  attn_kernel<<<dim3(32, 32), 256, 0, stream>>>(qkv, vt, aout);

  gemm_bt_kernel<0, 0><<<dim3(HID / 128, S_TOK / 128), 256, 0, stream>>>(
      aout, owbf, d_out, nullptr, S_TOK, HID, HID);
}